// Round 3
// baseline (681.095 us; speedup 1.0000x reference)
//
#include <hip/hip_runtime.h>
#include <math.h>

// VisualAttention, bf16x3 split-precision MFMA version.
//   t = text@W + b; attn = softmax(obj@t^T); out = attn@t
// obj[8,1024,512] text[8,4,1024,768]->[32768,768] W[768,512] b[512] -> out[8,1024,512] (fp32)
//
// Each fp32 x -> hi=bf16(x), lo=bf16(x-hi); A*B ~= Ah*Bh + Al*Bh + Ah*Bl (3 MFMAs).
// All GEMMs run as C = A[M,K] * B^T where B is [N,K] row-major (k contiguous);
// W and t are pre-transposed by a cheap tiled-transpose kernel.

typedef unsigned short u16;
typedef u16   u16x4  __attribute__((ext_vector_type(4)));
typedef u16   u16x8  __attribute__((ext_vector_type(8)));
typedef __bf16 bf16x8 __attribute__((ext_vector_type(8)));
typedef float f32x4  __attribute__((ext_vector_type(4)));

__device__ inline u16 f32_to_bf16_rne(float x) {
  unsigned u = __builtin_bit_cast(unsigned, x);
  return (u16)((u + 0x7FFFu + ((u >> 16) & 1u)) >> 16);
}
__device__ inline float bf16_to_f32(u16 h) {
  return __builtin_bit_cast(float, (unsigned)h << 16);
}

// ---------------- bf16x3 NT GEMM: C[M,N] = A[M,K] * B[N,K]^T (+bias) ----------------
// 128x128 tile, BK=32, 256 threads = 4 waves (2x2), 16x16x32 bf16 MFMA.
// LDS rows padded to 40 bf16 (80B = 5*16B: b128-aligned, 2-way bank alias = free).
template<bool ADD_BIAS>
__global__ __launch_bounds__(256, 2) void gemm_nt_bf16x3(
    const float* __restrict__ A, const float* __restrict__ B,
    float* __restrict__ C, const float* __restrict__ bias,
    int M, int N, int K, long sA, long sB, long sC)
{
  __shared__ __align__(16) u16 Ah[128][40];
  __shared__ __align__(16) u16 Al[128][40];
  __shared__ __align__(16) u16 Bh[128][40];
  __shared__ __align__(16) u16 Bl[128][40];

  const float* Ab = A + (long)blockIdx.z * sA;
  const float* Bb = B + (long)blockIdx.z * sB;
  float*       Cb = C + (long)blockIdx.z * sC;

  const int m0 = blockIdx.y * 128;
  const int n0 = blockIdx.x * 128;
  const int t    = threadIdx.x;
  const int lane = t & 63;
  const int w    = t >> 6;       // wave 0..3
  const int wm   = w >> 1;       // wave row (2x2 wave grid, 64x64 out each)
  const int wn   = w & 1;
  const int lr   = lane & 15;    // frag row/col within 16
  const int lg   = lane >> 4;    // k-group: k = lg*8 + j  [m89-verified]

  f32x4 acc[4][4];
  #pragma unroll
  for (int i = 0; i < 4; i++)
    #pragma unroll
    for (int j = 0; j < 4; j++) acc[i][j] = (f32x4){0.f, 0.f, 0.f, 0.f};

  for (int k0 = 0; k0 < K; k0 += 32) {
    // stage: 128 rows x 32 k of A and B, fp32 -> regs
    float4 av[4], bv[4];
    #pragma unroll
    for (int i = 0; i < 4; i++) {
      const int f   = t + 256 * i;      // 0..1023
      const int row = f >> 3;           // 0..127
      const int kq  = (f & 7) * 4;      // 0..28
      av[i] = *reinterpret_cast<const float4*>(Ab + (long)(m0 + row) * K + k0 + kq);
      bv[i] = *reinterpret_cast<const float4*>(Bb + (long)(n0 + row) * K + k0 + kq);
    }
    __syncthreads();   // previous iter's LDS reads done before overwrite
    #pragma unroll
    for (int i = 0; i < 4; i++) {
      const int f   = t + 256 * i;
      const int row = f >> 3;
      const int kq  = (f & 7) * 4;
      u16x4 ah4, al4, bh4, bl4;
      const float* ap = reinterpret_cast<const float*>(&av[i]);
      const float* bp = reinterpret_cast<const float*>(&bv[i]);
      #pragma unroll
      for (int c = 0; c < 4; c++) {
        u16 h = f32_to_bf16_rne(ap[c]);
        ah4[c] = h;
        al4[c] = f32_to_bf16_rne(ap[c] - bf16_to_f32(h));
        h = f32_to_bf16_rne(bp[c]);
        bh4[c] = h;
        bl4[c] = f32_to_bf16_rne(bp[c] - bf16_to_f32(h));
      }
      *reinterpret_cast<u16x4*>(&Ah[row][kq]) = ah4;
      *reinterpret_cast<u16x4*>(&Al[row][kq]) = al4;
      *reinterpret_cast<u16x4*>(&Bh[row][kq]) = bh4;
      *reinterpret_cast<u16x4*>(&Bl[row][kq]) = bl4;
    }
    __syncthreads();

    // fragments: 8 contiguous-k bf16 per lane  [m89/m91 layout]
    bf16x8 afh[4], afl[4], bfh[4], bfl[4];
    #pragma unroll
    for (int i = 0; i < 4; i++) {
      const int ar = wm * 64 + i * 16 + lr;
      const int br = wn * 64 + i * 16 + lr;
      afh[i] = __builtin_bit_cast(bf16x8, *reinterpret_cast<const u16x8*>(&Ah[ar][lg * 8]));
      afl[i] = __builtin_bit_cast(bf16x8, *reinterpret_cast<const u16x8*>(&Al[ar][lg * 8]));
      bfh[i] = __builtin_bit_cast(bf16x8, *reinterpret_cast<const u16x8*>(&Bh[br][lg * 8]));
      bfl[i] = __builtin_bit_cast(bf16x8, *reinterpret_cast<const u16x8*>(&Bl[br][lg * 8]));
    }
    #pragma unroll
    for (int i = 0; i < 4; i++)
      #pragma unroll
      for (int j = 0; j < 4; j++) {
        acc[i][j] = __builtin_amdgcn_mfma_f32_16x16x32_bf16(afl[i], bfh[j], acc[i][j], 0, 0, 0);
        acc[i][j] = __builtin_amdgcn_mfma_f32_16x16x32_bf16(afh[i], bfl[j], acc[i][j], 0, 0, 0);
        acc[i][j] = __builtin_amdgcn_mfma_f32_16x16x32_bf16(afh[i], bfh[j], acc[i][j], 0, 0, 0);
      }
  }

  // epilogue: C/D frag mapping col=lane&15, row=4*(lane>>4)+reg  [m89-verified]
  #pragma unroll
  for (int j = 0; j < 4; j++) {
    const int col = n0 + wn * 64 + j * 16 + lr;
    const float bj = ADD_BIAS ? bias[col] : 0.f;
    #pragma unroll
    for (int i = 0; i < 4; i++) {
      const int row = m0 + wm * 64 + i * 16 + lg * 4;
      #pragma unroll
      for (int r = 0; r < 4; r++)
        Cb[(long)(row + r) * N + col] = acc[i][j][r] + bj;
    }
  }
}

// ---------------- fp32 tiled transpose: out[C,R] = in[R,C]^T, batched ----------------
__global__ __launch_bounds__(256) void transpose_f32(
    const float* __restrict__ in, float* __restrict__ out,
    int R, int C, long sIn, long sOut)
{
  __shared__ float tile[32][33];
  in  += (long)blockIdx.z * sIn;
  out += (long)blockIdx.z * sOut;
  const int c  = blockIdx.x * 32 + threadIdx.x;
  const int r0 = blockIdx.y * 32 + threadIdx.y;
  #pragma unroll
  for (int j = 0; j < 32; j += 8)
    tile[threadIdx.y + j][threadIdx.x] = in[(long)(r0 + j) * C + c];
  __syncthreads();
  const int c2 = blockIdx.y * 32 + threadIdx.x;   // output col = original row
  const int r2 = blockIdx.x * 32 + threadIdx.y;   // output row = original col
  #pragma unroll
  for (int j = 0; j < 32; j += 8)
    out[(long)(r2 + j) * R + c2] = tile[threadIdx.x][threadIdx.y + j];
}

// ---------------- softmax over rows of 4096, in place ----------------
__device__ inline float wave_max(float x) {
  #pragma unroll
  for (int o = 1; o < 64; o <<= 1) x = fmaxf(x, __shfl_xor(x, o, 64));
  return x;
}
__device__ inline float wave_sum(float x) {
  #pragma unroll
  for (int o = 1; o < 64; o <<= 1) x += __shfl_xor(x, o, 64);
  return x;
}

__global__ __launch_bounds__(256) void softmax4096_kernel(float* __restrict__ attn)
{
  __shared__ float red[4];
  float* p = attn + (long)blockIdx.x * 4096;
  const int t = threadIdx.x;

  float4 v[4];
  float mx = -3.4e38f;
  #pragma unroll
  for (int i = 0; i < 4; i++) {
    v[i] = *reinterpret_cast<const float4*>(p + i * 1024 + t * 4);
    mx = fmaxf(mx, fmaxf(fmaxf(v[i].x, v[i].y), fmaxf(v[i].z, v[i].w)));
  }
  mx = wave_max(mx);
  if ((t & 63) == 0) red[t >> 6] = mx;
  __syncthreads();
  mx = fmaxf(fmaxf(red[0], red[1]), fmaxf(red[2], red[3]));
  __syncthreads();   // red reused below

  float s = 0.f;
  #pragma unroll
  for (int i = 0; i < 4; i++) {
    v[i].x = __expf(v[i].x - mx); s += v[i].x;
    v[i].y = __expf(v[i].y - mx); s += v[i].y;
    v[i].z = __expf(v[i].z - mx); s += v[i].z;
    v[i].w = __expf(v[i].w - mx); s += v[i].w;
  }
  s = wave_sum(s);
  if ((t & 63) == 0) red[t >> 6] = s;
  __syncthreads();
  const float r = 1.f / (red[0] + red[1] + red[2] + red[3]);

  #pragma unroll
  for (int i = 0; i < 4; i++) {
    v[i].x *= r; v[i].y *= r; v[i].z *= r; v[i].w *= r;
    *reinterpret_cast<float4*>(p + i * 1024 + t * 4) = v[i];
  }
}

extern "C" void kernel_launch(void* const* d_in, const int* in_sizes, int n_in,
                              void* d_out, int out_size, void* d_ws, size_t ws_size,
                              hipStream_t stream)
{
  const float* obj  = (const float*)d_in[0];  // [8,1024,512]
  const float* text = (const float*)d_in[1];  // [8,4,1024,768] -> [32768,768]
  const float* W    = (const float*)d_in[2];  // [768,512]
  const float* bias = (const float*)d_in[3];  // [512]
  float*       out  = (float*)d_out;          // [8,1024,512]

  // ws: t[32768,512] fp32 | attn[8,1024,4096] fp32 | tT[8,512,4096] fp32 | WT[512,768] fp32
  float* t    = (float*)d_ws;                  // 64 MB
  float* attn = t    + 32768L * 512;           // 128 MB
  float* tT   = attn + 8L * 1024 * 4096;       // 64 MB
  float* WT   = tT   + 8L * 512 * 4096;        // 1.5 MB   (total ~258 MB)

  // T0: WT[512,768] = W[768,512]^T
  transpose_f32<<<dim3(512 / 32, 768 / 32, 1), dim3(32, 8), 0, stream>>>(
      W, WT, 768, 512, 0L, 0L);
  // K1: t = text @ WT^T + bias    M=32768 N=512 K=768
  gemm_nt_bf16x3<true><<<dim3(512 / 128, 32768 / 128, 1), 256, 0, stream>>>(
      text, WT, t, bias, 32768, 512, 768, 0L, 0L, 0L);
  // T1: tT[b][512][4096] = t[b][4096][512]^T
  transpose_f32<<<dim3(512 / 32, 4096 / 32, 8), dim3(32, 8), 0, stream>>>(
      t, tT, 4096, 512, 4096L * 512, 512L * 4096);
  // K2: attn = obj @ t^T (per batch)   M=1024 N=4096 K=512
  gemm_nt_bf16x3<false><<<dim3(4096 / 128, 1024 / 128, 8), 256, 0, stream>>>(
      obj, t, attn, nullptr, 1024, 4096, 512,
      1024L * 512, 4096L * 512, 1024L * 4096);
  // K3: row softmax, 8192 rows of 4096
  softmax4096_kernel<<<8192, 256, 0, stream>>>(attn);
  // K4: out = attn @ tT^T (per batch)  M=1024 N=512 K=4096
  gemm_nt_bf16x3<false><<<dim3(512 / 128, 1024 / 128, 8), 256, 0, stream>>>(
      attn, tT, out, nullptr, 1024, 512, 4096,
      1024L * 4096, 512L * 4096, 1024L * 512);
}

// Round 6
// 557.774 us; speedup vs baseline: 1.2211x; 1.2211x over previous
//
#include <hip/hip_runtime.h>
#include <math.h>

// VisualAttention, bf16x3 split-precision MFMA, 2-phase pipelined (T3-min).
//   t = text@W + b; attn = softmax(obj@t^T); out = attn@t
// obj[8,1024,512] text[32768,768] W[768,512] b[512] -> out[8,1024,512] (fp32)
// fp32 x -> hi=bf16(x), lo=bf16(x-hi); A*B ~= Ah*Bh + Al*Bh + Ah*Bl (3 MFMAs).
// All GEMMs NT (B=[N,K], k contiguous). ws layout identical to round 3 (258MB, known-good).

typedef unsigned short u16;
typedef u16   u16x4  __attribute__((ext_vector_type(4)));
typedef u16   u16x8  __attribute__((ext_vector_type(8)));
typedef __bf16 bf16x8 __attribute__((ext_vector_type(8)));
typedef float f32x4  __attribute__((ext_vector_type(4)));

// compiler-friendly split (emits v_cvt_pk_bf16_f32 pairs; m240: don't hand-roll)
__device__ inline void split4(const float4 v, u16x4* h4, u16x4* l4) {
  const float xs[4] = {v.x, v.y, v.z, v.w};
  #pragma unroll
  for (int c = 0; c < 4; c++) {
    __bf16 hb = (__bf16)xs[c];
    __bf16 lb = (__bf16)(xs[c] - (float)hb);
    (*h4)[c] = __builtin_bit_cast(u16, hb);
    (*l4)[c] = __builtin_bit_cast(u16, lb);
  }
}

// ---------------- bf16x3 NT GEMM, double-buffered LDS, 1 barrier/k-step ----------------
// 128x128 tile, BK=32, 256 thr = 4 waves (2x2). LDS rows padded to 40 u16 (80B).
template<bool ADD_BIAS>
__global__ __launch_bounds__(256, 2) void gemm_nt_bf16x3(
    const float* __restrict__ A, const float* __restrict__ B,
    float* __restrict__ C, const float* __restrict__ bias,
    int M, int N, int K, long sA, long sB, long sC)
{
  __shared__ __align__(16) u16 Ah[2][128][40];
  __shared__ __align__(16) u16 Al[2][128][40];
  __shared__ __align__(16) u16 Bh[2][128][40];
  __shared__ __align__(16) u16 Bl[2][128][40];   // 80 KB total -> 2 blocks/CU

  const float* Ab = A + (long)blockIdx.z * sA;
  const float* Bb = B + (long)blockIdx.z * sB;
  float*       Cb = C + (long)blockIdx.z * sC;

  const int m0 = blockIdx.y * 128;
  const int n0 = blockIdx.x * 128;
  const int t    = threadIdx.x;
  const int lane = t & 63;
  const int w    = t >> 6;
  const int wm   = w >> 1;       // 2x2 wave grid, 64x64 out each
  const int wn   = w & 1;
  const int lr   = lane & 15;    // frag row/col  [m89/m91 layout]
  const int lg   = lane >> 4;    // k-group: k = lg*8 + j

  f32x4 acc[4][4];
  #pragma unroll
  for (int i = 0; i < 4; i++)
    #pragma unroll
    for (int j = 0; j < 4; j++) acc[i][j] = (f32x4){0.f, 0.f, 0.f, 0.f};

  float4 av[4], bv[4];

  #define LOADK(K0)                                                                 \
    _Pragma("unroll")                                                               \
    for (int i = 0; i < 4; i++) {                                                   \
      const int f   = t + 256 * i;                                                  \
      const int row = f >> 3;                                                       \
      const int kq  = (f & 7) * 4;                                                  \
      av[i] = *reinterpret_cast<const float4*>(Ab + (long)(m0 + row) * K + (K0) + kq); \
      bv[i] = *reinterpret_cast<const float4*>(Bb + (long)(n0 + row) * K + (K0) + kq); \
    }

  #define CONVWRITE(BUF)                                                            \
    _Pragma("unroll")                                                               \
    for (int i = 0; i < 4; i++) {                                                   \
      const int f   = t + 256 * i;                                                  \
      const int row = f >> 3;                                                       \
      const int kq  = (f & 7) * 4;                                                  \
      u16x4 h4, l4;                                                                 \
      split4(av[i], &h4, &l4);                                                      \
      *reinterpret_cast<u16x4*>(&Ah[BUF][row][kq]) = h4;                            \
      *reinterpret_cast<u16x4*>(&Al[BUF][row][kq]) = l4;                            \
      split4(bv[i], &h4, &l4);                                                      \
      *reinterpret_cast<u16x4*>(&Bh[BUF][row][kq]) = h4;                            \
      *reinterpret_cast<u16x4*>(&Bl[BUF][row][kq]) = l4;                            \
    }

  // prologue: stage k-tile 0 into buf 0
  LOADK(0)
  CONVWRITE(0)
  __syncthreads();

  const int nk = K >> 5;
  for (int kt = 0; kt < nk; ++kt) {
    const int cur = kt & 1;
    // issue next tile's global loads first: latency hides under MFMA phase
    if (kt + 1 < nk) { LOADK((kt + 1) << 5) }

    // fragments from buf[cur] + 48 MFMA
    bf16x8 afh[4], afl[4];
    #pragma unroll
    for (int i = 0; i < 4; i++) {
      const int ar = wm * 64 + i * 16 + lr;
      afh[i] = __builtin_bit_cast(bf16x8, *reinterpret_cast<const u16x8*>(&Ah[cur][ar][lg * 8]));
      afl[i] = __builtin_bit_cast(bf16x8, *reinterpret_cast<const u16x8*>(&Al[cur][ar][lg * 8]));
    }
    #pragma unroll
    for (int j = 0; j < 4; j++) {
      const int br = wn * 64 + j * 16 + lr;
      bf16x8 bh = __builtin_bit_cast(bf16x8, *reinterpret_cast<const u16x8*>(&Bh[cur][br][lg * 8]));
      bf16x8 bl = __builtin_bit_cast(bf16x8, *reinterpret_cast<const u16x8*>(&Bl[cur][br][lg * 8]));
      #pragma unroll
      for (int i = 0; i < 4; i++) {
        acc[i][j] = __builtin_amdgcn_mfma_f32_16x16x32_bf16(afl[i], bh, acc[i][j], 0, 0, 0);
        acc[i][j] = __builtin_amdgcn_mfma_f32_16x16x32_bf16(afh[i], bl, acc[i][j], 0, 0, 0);
        acc[i][j] = __builtin_amdgcn_mfma_f32_16x16x32_bf16(afh[i], bh, acc[i][j], 0, 0, 0);
      }
    }

    // convert+write next tile into the other buffer; reads of buf[cur^1] all
    // completed before the barrier that ended iter kt-1 (safe: race-audited)
    if (kt + 1 < nk) { CONVWRITE(cur ^ 1) }
    __syncthreads();
  }
  #undef LOADK
  #undef CONVWRITE

  // epilogue: C/D frag col=lane&15, row=4*(lane>>4)+reg  [m89-verified]
  #pragma unroll
  for (int j = 0; j < 4; j++) {
    const int col = n0 + wn * 64 + j * 16 + lr;
    const float bj = ADD_BIAS ? bias[col] : 0.f;
    #pragma unroll
    for (int i = 0; i < 4; i++) {
      const int row = m0 + wm * 64 + i * 16 + lg * 4;
      #pragma unroll
      for (int r = 0; r < 4; r++)
        Cb[(long)(row + r) * N + col] = acc[i][j][r] + bj;
    }
  }
}

// ---------------- fp32 tiled transpose: out[C,R] = in[R,C]^T, batched ----------------
__global__ __launch_bounds__(256) void transpose_f32(
    const float* __restrict__ in, float* __restrict__ out,
    int R, int C, long sIn, long sOut)
{
  __shared__ float tile[32][33];
  in  += (long)blockIdx.z * sIn;
  out += (long)blockIdx.z * sOut;
  const int c  = blockIdx.x * 32 + threadIdx.x;
  const int r0 = blockIdx.y * 32 + threadIdx.y;
  #pragma unroll
  for (int j = 0; j < 32; j += 8)
    tile[threadIdx.y + j][threadIdx.x] = in[(long)(r0 + j) * C + c];
  __syncthreads();
  const int c2 = blockIdx.y * 32 + threadIdx.x;
  const int r2 = blockIdx.x * 32 + threadIdx.y;
  #pragma unroll
  for (int j = 0; j < 32; j += 8)
    out[(long)(r2 + j) * R + c2] = tile[threadIdx.x][threadIdx.y + j];
}

// ---------------- softmax over rows of 4096, in place ----------------
__device__ inline float wave_max(float x) {
  #pragma unroll
  for (int o = 1; o < 64; o <<= 1) x = fmaxf(x, __shfl_xor(x, o, 64));
  return x;
}
__device__ inline float wave_sum(float x) {
  #pragma unroll
  for (int o = 1; o < 64; o <<= 1) x += __shfl_xor(x, o, 64);
  return x;
}

__global__ __launch_bounds__(256) void softmax4096_kernel(float* __restrict__ attn)
{
  __shared__ float red[4];
  float* p = attn + (long)blockIdx.x * 4096;
  const int t = threadIdx.x;

  float4 v[4];
  float mx = -3.4e38f;
  #pragma unroll
  for (int i = 0; i < 4; i++) {
    v[i] = *reinterpret_cast<const float4*>(p + i * 1024 + t * 4);
    mx = fmaxf(mx, fmaxf(fmaxf(v[i].x, v[i].y), fmaxf(v[i].z, v[i].w)));
  }
  mx = wave_max(mx);
  if ((t & 63) == 0) red[t >> 6] = mx;
  __syncthreads();
  mx = fmaxf(fmaxf(red[0], red[1]), fmaxf(red[2], red[3]));
  __syncthreads();

  float s = 0.f;
  #pragma unroll
  for (int i = 0; i < 4; i++) {
    v[i].x = __expf(v[i].x - mx); s += v[i].x;
    v[i].y = __expf(v[i].y - mx); s += v[i].y;
    v[i].z = __expf(v[i].z - mx); s += v[i].z;
    v[i].w = __expf(v[i].w - mx); s += v[i].w;
  }
  s = wave_sum(s);
  if ((t & 63) == 0) red[t >> 6] = s;
  __syncthreads();
  const float r = 1.f / (red[0] + red[1] + red[2] + red[3]);

  #pragma unroll
  for (int i = 0; i < 4; i++) {
    v[i].x *= r; v[i].y *= r; v[i].z *= r; v[i].w *= r;
    *reinterpret_cast<float4*>(p + i * 1024 + t * 4) = v[i];
  }
}

extern "C" void kernel_launch(void* const* d_in, const int* in_sizes, int n_in,
                              void* d_out, int out_size, void* d_ws, size_t ws_size,
                              hipStream_t stream)
{
  const float* obj  = (const float*)d_in[0];  // [8,1024,512]
  const float* text = (const float*)d_in[1];  // [32768,768]
  const float* W    = (const float*)d_in[2];  // [768,512]
  const float* bias = (const float*)d_in[3];  // [512]
  float*       out  = (float*)d_out;          // [8,1024,512]

  // ws: t[32768,512] | attn[8,1024,4096] | tT[8,512,4096] | WT[512,768]  (~258 MB, known-good)
  float* t    = (float*)d_ws;
  float* attn = t    + 32768L * 512;
  float* tT   = attn + 8L * 1024 * 4096;
  float* WT   = tT   + 8L * 512 * 4096;

  // T0: WT = W^T
  transpose_f32<<<dim3(512 / 32, 768 / 32, 1), dim3(32, 8), 0, stream>>>(
      W, WT, 768, 512, 0L, 0L);
  // K1: t = text @ WT^T + bias    M=32768 N=512 K=768
  gemm_nt_bf16x3<true><<<dim3(512 / 128, 32768 / 128, 1), 256, 0, stream>>>(
      text, WT, t, bias, 32768, 512, 768, 0L, 0L, 0L);
  // T1: tT[b] = t[b]^T
  transpose_f32<<<dim3(512 / 32, 4096 / 32, 8), dim3(32, 8), 0, stream>>>(
      t, tT, 4096, 512, 4096L * 512, 512L * 4096);
  // K2: attn = obj @ t^T (per batch)   M=1024 N=4096 K=512
  gemm_nt_bf16x3<false><<<dim3(4096 / 128, 1024 / 128, 8), 256, 0, stream>>>(
      obj, t, attn, nullptr, 1024, 4096, 512,
      1024L * 512, 4096L * 512, 1024L * 4096);
  // K3: row softmax, 8192 rows of 4096
  softmax4096_kernel<<<8192, 256, 0, stream>>>(attn);
  // K4: out = attn @ tT^T (per batch)  M=1024 N=512 K=4096
  gemm_nt_bf16x3<false><<<dim3(512 / 128, 1024 / 128, 8), 256, 0, stream>>>(
      attn, tT, out, nullptr, 1024, 512, 4096,
      1024L * 4096, 512L * 4096, 1024L * 512);
}

// Round 7
// 553.124 us; speedup vs baseline: 1.2314x; 1.0084x over previous
//
#include <hip/hip_runtime.h>
#include <math.h>

// VisualAttention, bf16x3 split-precision MFMA, 2-phase pipelined, 8-wave blocks.
//   t = text@W + b; attn = softmax(obj@t^T); out = attn@t
// obj[8,1024,512] text[32768,768] W[768,512] b[512] -> out[8,1024,512] (fp32)
// fp32 x -> hi=bf16(x), lo=bf16(x-hi); A*B ~= Ah*Bh + Al*Bh + Ah*Bl (3 MFMAs).
// All GEMMs NT (B=[N,K], k contiguous). ws layout identical to round 3 (258MB, known-good).
//
// Round 7 changes (theory: K4 latency-serialized at 1 wave/SIMD + LDS write conflicts):
//  - 512 threads / 8 waves (2x4 wave grid, 64x32 out per wave): 2 waves/SIMD at 1 block/CU
//  - chunk-8 staging: one 16B u16x8 LDS write per array, banks (20r+4q)%32 balanced
//  - term-outer MFMA order: dependent-acc spacing 4 MFMAs > MFMA latency

typedef unsigned short u16;
typedef u16   u16x4  __attribute__((ext_vector_type(4)));
typedef u16   u16x8  __attribute__((ext_vector_type(8)));
typedef __bf16 bf16x8 __attribute__((ext_vector_type(8)));
typedef float f32x4  __attribute__((ext_vector_type(4)));

// compiler-friendly split (emits v_cvt_pk_bf16_f32 pairs; m240: don't hand-roll)
__device__ inline void split4(const float4 v, u16x4* h4, u16x4* l4) {
  const float xs[4] = {v.x, v.y, v.z, v.w};
  #pragma unroll
  for (int c = 0; c < 4; c++) {
    __bf16 hb = (__bf16)xs[c];
    __bf16 lb = (__bf16)(xs[c] - (float)hb);
    (*h4)[c] = __builtin_bit_cast(u16, hb);
    (*l4)[c] = __builtin_bit_cast(u16, lb);
  }
}
__device__ inline u16x8 cat8(u16x4 a, u16x4 b) {
  u16x8 r;
  r[0]=a[0]; r[1]=a[1]; r[2]=a[2]; r[3]=a[3];
  r[4]=b[0]; r[5]=b[1]; r[6]=b[2]; r[7]=b[3];
  return r;
}

// ---------------- bf16x3 NT GEMM, double-buffered LDS, 1 barrier/k-step ----------------
// 128x128 tile, BK=32, 512 thr = 8 waves (2x4). LDS rows padded to 40 u16 (80B).
template<bool ADD_BIAS>
__global__ __launch_bounds__(512, 4) void gemm_nt_bf16x3(
    const float* __restrict__ A, const float* __restrict__ B,
    float* __restrict__ C, const float* __restrict__ bias,
    int M, int N, int K, long sA, long sB, long sC)
{
  __shared__ __align__(16) u16 Ah[2][128][40];
  __shared__ __align__(16) u16 Al[2][128][40];
  __shared__ __align__(16) u16 Bh[2][128][40];
  __shared__ __align__(16) u16 Bl[2][128][40];   // 80 KB -> 2 blocks/CU (LDS)

  const float* Ab = A + (long)blockIdx.z * sA;
  const float* Bb = B + (long)blockIdx.z * sB;
  float*       Cb = C + (long)blockIdx.z * sC;

  const int m0 = blockIdx.y * 128;
  const int n0 = blockIdx.x * 128;
  const int t    = threadIdx.x;
  const int lane = t & 63;
  const int w    = t >> 6;       // wave 0..7
  const int wm   = w >> 2;       // 2 wave-rows x 4 wave-cols; 64x32 out per wave
  const int wn   = w & 3;
  const int lr   = lane & 15;    // frag row/col  [m89/m91 layout]
  const int lg   = lane >> 4;    // k-group: k = lg*8 + j

  // staging: thread t owns row=t>>2 (0..127), kc=(t&3)*8 (8 contiguous k)
  const int srow = t >> 2;
  const int skc  = (t & 3) * 8;

  f32x4 acc[4][2];
  #pragma unroll
  for (int i = 0; i < 4; i++)
    #pragma unroll
    for (int j = 0; j < 2; j++) acc[i][j] = (f32x4){0.f, 0.f, 0.f, 0.f};

  float4 av0, av1, bv0, bv1;

  #define LOADK(K0)                                                                   \
    {                                                                                 \
      const float* ap = Ab + (long)(m0 + srow) * K + (K0) + skc;                      \
      const float* bp = Bb + (long)(n0 + srow) * K + (K0) + skc;                      \
      av0 = *reinterpret_cast<const float4*>(ap);                                     \
      av1 = *reinterpret_cast<const float4*>(ap + 4);                                 \
      bv0 = *reinterpret_cast<const float4*>(bp);                                     \
      bv1 = *reinterpret_cast<const float4*>(bp + 4);                                 \
    }

  #define CONVWRITE(BUF)                                                             \
    {                                                                                 \
      u16x4 h0, l0, h1, l1;                                                           \
      split4(av0, &h0, &l0); split4(av1, &h1, &l1);                                   \
      *reinterpret_cast<u16x8*>(&Ah[BUF][srow][skc]) = cat8(h0, h1);                  \
      *reinterpret_cast<u16x8*>(&Al[BUF][srow][skc]) = cat8(l0, l1);                  \
      split4(bv0, &h0, &l0); split4(bv1, &h1, &l1);                                   \
      *reinterpret_cast<u16x8*>(&Bh[BUF][srow][skc]) = cat8(h0, h1);                  \
      *reinterpret_cast<u16x8*>(&Bl[BUF][srow][skc]) = cat8(l0, l1);                  \
    }

  // prologue: stage k-tile 0 into buf 0
  LOADK(0)
  CONVWRITE(0)
  __syncthreads();

  const int nk = K >> 5;
  for (int kt = 0; kt < nk; ++kt) {
    const int cur = kt & 1;
    // issue next tile's global loads first: latency hides under MFMA phase
    if (kt + 1 < nk) { LOADK((kt + 1) << 5) }

    // fragments from buf[cur]
    bf16x8 afh[4], afl[4], bfh[2], bfl[2];
    #pragma unroll
    for (int i = 0; i < 4; i++) {
      const int ar = wm * 64 + i * 16 + lr;
      afh[i] = __builtin_bit_cast(bf16x8, *reinterpret_cast<const u16x8*>(&Ah[cur][ar][lg * 8]));
      afl[i] = __builtin_bit_cast(bf16x8, *reinterpret_cast<const u16x8*>(&Al[cur][ar][lg * 8]));
    }
    #pragma unroll
    for (int j = 0; j < 2; j++) {
      const int br = wn * 32 + j * 16 + lr;
      bfh[j] = __builtin_bit_cast(bf16x8, *reinterpret_cast<const u16x8*>(&Bh[cur][br][lg * 8]));
      bfl[j] = __builtin_bit_cast(bf16x8, *reinterpret_cast<const u16x8*>(&Bl[cur][br][lg * 8]));
    }

    // term-outer MFMA: same-acc reuse separated by 4 independent MFMAs
    #pragma unroll
    for (int j = 0; j < 2; j++) {
      #pragma unroll
      for (int i = 0; i < 4; i++)
        acc[i][j] = __builtin_amdgcn_mfma_f32_16x16x32_bf16(afl[i], bfh[j], acc[i][j], 0, 0, 0);
      #pragma unroll
      for (int i = 0; i < 4; i++)
        acc[i][j] = __builtin_amdgcn_mfma_f32_16x16x32_bf16(afh[i], bfl[j], acc[i][j], 0, 0, 0);
      #pragma unroll
      for (int i = 0; i < 4; i++)
        acc[i][j] = __builtin_amdgcn_mfma_f32_16x16x32_bf16(afh[i], bfh[j], acc[i][j], 0, 0, 0);
    }

    // convert+write next tile into the other buffer (its readers finished
    // before the barrier that ended iter kt-1; race-audited)
    if (kt + 1 < nk) { CONVWRITE(cur ^ 1) }
    __syncthreads();
  }
  #undef LOADK
  #undef CONVWRITE

  // epilogue: C/D frag col=lane&15, row=4*(lane>>4)+reg  [m89-verified]
  #pragma unroll
  for (int j = 0; j < 2; j++) {
    const int col = n0 + wn * 32 + j * 16 + lr;
    const float bj = ADD_BIAS ? bias[col] : 0.f;
    #pragma unroll
    for (int i = 0; i < 4; i++) {
      const int row = m0 + wm * 64 + i * 16 + lg * 4;
      #pragma unroll
      for (int r = 0; r < 4; r++)
        Cb[(long)(row + r) * N + col] = acc[i][j][r] + bj;
    }
  }
}

// ---------------- fp32 tiled transpose: out[C,R] = in[R,C]^T, batched ----------------
__global__ __launch_bounds__(256) void transpose_f32(
    const float* __restrict__ in, float* __restrict__ out,
    int R, int C, long sIn, long sOut)
{
  __shared__ float tile[32][33];
  in  += (long)blockIdx.z * sIn;
  out += (long)blockIdx.z * sOut;
  const int c  = blockIdx.x * 32 + threadIdx.x;
  const int r0 = blockIdx.y * 32 + threadIdx.y;
  #pragma unroll
  for (int j = 0; j < 32; j += 8)
    tile[threadIdx.y + j][threadIdx.x] = in[(long)(r0 + j) * C + c];
  __syncthreads();
  const int c2 = blockIdx.y * 32 + threadIdx.x;
  const int r2 = blockIdx.x * 32 + threadIdx.y;
  #pragma unroll
  for (int j = 0; j < 32; j += 8)
    out[(long)(r2 + j) * R + c2] = tile[threadIdx.x][threadIdx.y + j];
}

// ---------------- softmax over rows of 4096, in place ----------------
__device__ inline float wave_max(float x) {
  #pragma unroll
  for (int o = 1; o < 64; o <<= 1) x = fmaxf(x, __shfl_xor(x, o, 64));
  return x;
}
__device__ inline float wave_sum(float x) {
  #pragma unroll
  for (int o = 1; o < 64; o <<= 1) x += __shfl_xor(x, o, 64);
  return x;
}

__global__ __launch_bounds__(256) void softmax4096_kernel(float* __restrict__ attn)
{
  __shared__ float red[4];
  float* p = attn + (long)blockIdx.x * 4096;
  const int t = threadIdx.x;

  float4 v[4];
  float mx = -3.4e38f;
  #pragma unroll
  for (int i = 0; i < 4; i++) {
    v[i] = *reinterpret_cast<const float4*>(p + i * 1024 + t * 4);
    mx = fmaxf(mx, fmaxf(fmaxf(v[i].x, v[i].y), fmaxf(v[i].z, v[i].w)));
  }
  mx = wave_max(mx);
  if ((t & 63) == 0) red[t >> 6] = mx;
  __syncthreads();
  mx = fmaxf(fmaxf(red[0], red[1]), fmaxf(red[2], red[3]));
  __syncthreads();

  float s = 0.f;
  #pragma unroll
  for (int i = 0; i < 4; i++) {
    v[i].x = __expf(v[i].x - mx); s += v[i].x;
    v[i].y = __expf(v[i].y - mx); s += v[i].y;
    v[i].z = __expf(v[i].z - mx); s += v[i].z;
    v[i].w = __expf(v[i].w - mx); s += v[i].w;
  }
  s = wave_sum(s);
  if ((t & 63) == 0) red[t >> 6] = s;
  __syncthreads();
  const float r = 1.f / (red[0] + red[1] + red[2] + red[3]);

  #pragma unroll
  for (int i = 0; i < 4; i++) {
    v[i].x *= r; v[i].y *= r; v[i].z *= r; v[i].w *= r;
    *reinterpret_cast<float4*>(p + i * 1024 + t * 4) = v[i];
  }
}

extern "C" void kernel_launch(void* const* d_in, const int* in_sizes, int n_in,
                              void* d_out, int out_size, void* d_ws, size_t ws_size,
                              hipStream_t stream)
{
  const float* obj  = (const float*)d_in[0];  // [8,1024,512]
  const float* text = (const float*)d_in[1];  // [32768,768]
  const float* W    = (const float*)d_in[2];  // [768,512]
  const float* bias = (const float*)d_in[3];  // [512]
  float*       out  = (float*)d_out;          // [8,1024,512]

  // ws: t[32768,512] | attn[8,1024,4096] | tT[8,512,4096] | WT[512,768]  (~258 MB, known-good)
  float* t    = (float*)d_ws;
  float* attn = t    + 32768L * 512;
  float* tT   = attn + 8L * 1024 * 4096;
  float* WT   = tT   + 8L * 512 * 4096;

  // T0: WT = W^T
  transpose_f32<<<dim3(512 / 32, 768 / 32, 1), dim3(32, 8), 0, stream>>>(
      W, WT, 768, 512, 0L, 0L);
  // K1: t = text @ WT^T + bias    M=32768 N=512 K=768
  gemm_nt_bf16x3<true><<<dim3(512 / 128, 32768 / 128, 1), 512, 0, stream>>>(
      text, WT, t, bias, 32768, 512, 768, 0L, 0L, 0L);
  // T1: tT[b] = t[b]^T
  transpose_f32<<<dim3(512 / 32, 4096 / 32, 8), dim3(32, 8), 0, stream>>>(
      t, tT, 4096, 512, 4096L * 512, 512L * 4096);
  // K2: attn = obj @ t^T (per batch)   M=1024 N=4096 K=512
  gemm_nt_bf16x3<false><<<dim3(4096 / 128, 1024 / 128, 8), 512, 0, stream>>>(
      obj, t, attn, nullptr, 1024, 4096, 512,
      1024L * 512, 4096L * 512, 1024L * 4096);
  // K3: row softmax, 8192 rows of 4096
  softmax4096_kernel<<<8192, 256, 0, stream>>>(attn);
  // K4: out = attn @ tT^T (per batch)  M=1024 N=512 K=4096
  gemm_nt_bf16x3<false><<<dim3(512 / 128, 1024 / 128, 8), 512, 0, stream>>>(
      attn, tT, out, nullptr, 1024, 512, 4096,
      1024L * 4096, 512L * 4096, 1024L * 512);
}